// Round 1
// baseline (18.761 us; speedup 1.0000x reference)
//
#include <hip/hip_runtime.h>

// GRU single-step cell over N = B*A independent rows of 9 floats.
// Each thread: 4 rows = 36 floats = 9 float4 loads, 1 float4 store.
__global__ __launch_bounds__(256) void gru_cell_kernel(
    const float* __restrict__ in,    // (N, 9)
    const float* __restrict__ w_ih,  // (3, 8)
    const float* __restrict__ w_hh,  // (3, 1)
    const float* __restrict__ b_ih,  // (3,)
    const float* __restrict__ b_hh,  // (3,)
    const float* __restrict__ w_out, // (1, 1)
    const float* __restrict__ b_out, // (1,)
    float* __restrict__ out,         // (N,)
    int n_rows)
{
    const int tid = blockIdx.x * blockDim.x + threadIdx.x;
    const int row0 = tid * 4;
    if (row0 >= n_rows) return;

    // Uniform-address weight loads (compiler emits s_load; broadcast via SGPR).
    float wih[3][8];
#pragma unroll
    for (int g = 0; g < 3; ++g)
#pragma unroll
        for (int c = 0; c < 8; ++c)
            wih[g][c] = w_ih[g * 8 + c];
    const float whh0 = w_hh[0], whh1 = w_hh[1], whh2 = w_hh[2];
    const float bi0 = b_ih[0], bi1 = b_ih[1], bi2 = b_ih[2];
    const float bh0 = b_hh[0], bh1 = b_hh[1], bh2 = b_hh[2];
    const float wo = w_out[0], bo = b_out[0];

    // 4 rows * 9 floats = 36 floats = 9 float4 (16B-aligned: row0*9*4 = 144B multiple).
    float4 v[9];
    const float4* src = reinterpret_cast<const float4*>(in + (size_t)row0 * 9);
#pragma unroll
    for (int i = 0; i < 9; ++i) v[i] = src[i];
    const float* f = reinterpret_cast<const float*>(v);

    float4 o;
    float* op = reinterpret_cast<float*>(&o);
#pragma unroll
    for (int r = 0; r < 4; ++r) {
        const float* row = f + r * 9;   // compile-time indices after unroll
        const float h = row[0];
        float gi0 = bi0, gi1 = bi1, gi2 = bi2;
#pragma unroll
        for (int c = 0; c < 8; ++c) {
            const float x = row[1 + c];
            gi0 = fmaf(x, wih[0][c], gi0);
            gi1 = fmaf(x, wih[1][c], gi1);
            gi2 = fmaf(x, wih[2][c], gi2);
        }
        const float gh0 = fmaf(h, whh0, bh0);
        const float gh1 = fmaf(h, whh1, bh1);
        const float gh2 = fmaf(h, whh2, bh2);

        const float rg = 1.0f / (1.0f + __expf(-(gi0 + gh0)));
        const float z  = 1.0f / (1.0f + __expf(-(gi1 + gh1)));
        const float nn = tanhf(fmaf(rg, gh2, gi2));
        const float hn = (1.0f - z) * nn + z * h;
        op[r] = fmaf(hn, wo, bo);
    }
    *reinterpret_cast<float4*>(out + row0) = o;
}

extern "C" void kernel_launch(void* const* d_in, const int* in_sizes, int n_in,
                              void* d_out, int out_size, void* d_ws, size_t ws_size,
                              hipStream_t stream) {
    (void)n_in; (void)d_ws; (void)ws_size;
    const float* in    = (const float*)d_in[0];
    const float* w_ih  = (const float*)d_in[1];
    const float* w_hh  = (const float*)d_in[2];
    const float* b_ih  = (const float*)d_in[3];
    const float* b_hh  = (const float*)d_in[4];
    const float* w_out = (const float*)d_in[5];
    const float* b_out = (const float*)d_in[6];
    float* out = (float*)d_out;

    const int n_rows = out_size;            // B*A = 2,097,152
    const int rows_per_thread = 4;
    const int block = 256;
    const int threads = (n_rows + rows_per_thread - 1) / rows_per_thread;
    const int grid = (threads + block - 1) / block;  // 2048

    gru_cell_kernel<<<grid, block, 0, stream>>>(in, w_ih, w_hh, b_ih, b_hh,
                                                w_out, b_out, out, n_rows);
}